// Round 1
// baseline (812.811 us; speedup 1.0000x reference)
//
#include <hip/hip_runtime.h>

// Problem constants (from reference): B=4, L=4096, V=8192.
#define BB 4
#define LL 4096
#define VV 8192
#define NN (BB * LL)          // 16384 tokens
#define SIGMA_SCALE 0.01f

// Bucketing: tokens grouped by idx >> 6 (64-wide column buckets).
#define CW 64                 // columns per bucket / tile width
#define NB (VV / CW)          // 128 buckets
#define VT 128                // v-rows per tile

// out[b,l,v] = W[v, idx[b,l]] + 0.01*sigma[b]*rowsum(W)[v] + bias[v]

// ---------------------------------------------------------------------------
// Kernel 1: per-row sum of W, fused into per-(b,v) additive table:
//   add[b*V + v] = SIGMA_SCALE * sigma[b] * sum_j W[v,j] + bias[v]
__global__ void rowsum_kernel(const float* __restrict__ W,
                              const float* __restrict__ sigma,
                              const float* __restrict__ bias,
                              float* __restrict__ add) {
    __shared__ float red[256];
    const int v = blockIdx.x;
    const float4* row4 = (const float4*)(W + (size_t)v * VV);
    float s = 0.f;
#pragma unroll
    for (int j = threadIdx.x; j < VV / 4; j += 256) {
        float4 x = row4[j];
        s += x.x + x.y + x.z + x.w;
    }
    red[threadIdx.x] = s;
    __syncthreads();
    for (int off = 128; off > 0; off >>= 1) {
        if (threadIdx.x < off) red[threadIdx.x] += red[threadIdx.x + off];
        __syncthreads();
    }
    if (threadIdx.x < BB) {
        add[threadIdx.x * VV + v] =
            SIGMA_SCALE * sigma[threadIdx.x] * red[0] + bias[v];
    }
}

// ---------------------------------------------------------------------------
// Kernel 2: bucket the 16384 tokens by column-tile (idx >> 6).
// Single block, 256 threads. Output: sorted[] packed as (n<<13)|c,
// offsets[NB+1] bucket boundaries.
__global__ void bucket_kernel(const int* __restrict__ idx,
                              int* __restrict__ sorted,
                              int* __restrict__ offsets) {
    __shared__ int hist[NB];
    __shared__ int base[NB + 1];
    __shared__ int cursor[NB];
    const int tid = threadIdx.x;
    for (int i = tid; i < NB; i += 256) hist[i] = 0;
    __syncthreads();
    for (int n = tid; n < NN; n += 256) {
        int c = idx[n];
        c = min(max(c, 0), VV - 1);
        atomicAdd(&hist[c >> 6], 1);
    }
    __syncthreads();
    if (tid == 0) {
        int s = 0;
        for (int i = 0; i < NB; ++i) { base[i] = s; s += hist[i]; }
        base[NB] = s;
    }
    __syncthreads();
    for (int i = tid; i <= NB; i += 256) offsets[i] = base[i];
    for (int i = tid; i < NB; i += 256) cursor[i] = 0;
    __syncthreads();
    for (int n = tid; n < NN; n += 256) {
        int c = idx[n];
        c = min(max(c, 0), VV - 1);
        const int bkt = c >> 6;
        const int pos = base[bkt] + atomicAdd(&cursor[bkt], 1);
        sorted[pos] = (n << 13) | c;
    }
}

// ---------------------------------------------------------------------------
// Kernel 3: fused transpose-gather. Block (cb, vb) loads W[vb*VT .. +VT,
// cb*64 .. +64] into LDS once (coalesced), then for each token in bucket cb
// writes out[n, vb*VT .. +VT] = tile[:, c_local] + add[b, vb*VT .. +VT].
// W is read from HBM exactly once across the whole grid; no WT round-trip.
__global__ __launch_bounds__(256) void gather_fused_kernel(
    const int* __restrict__ sorted, const int* __restrict__ offsets,
    const float* __restrict__ W, const float* __restrict__ add,
    float* __restrict__ out) {
    __shared__ float tile[VT][CW + 1];   // +1 pad: column read conflict-free
    __shared__ float addl[BB][VT];
    const int cb = blockIdx.x;           // 0..NB-1
    const int vb = blockIdx.y;           // 0..VV/VT-1
    const int c0 = cb * CW;
    const int v0 = vb * VT;
    const int tid = threadIdx.x;         // 0..255

    // Stage W tile: 16 lanes x float4 = one 256B row segment; 16 rows/pass.
    {
        const int r = tid >> 4;          // 0..15
        const int q = tid & 15;          // float4 slot within row
#pragma unroll
        for (int k = 0; k < VT; k += 16) {
            float4 x = *(const float4*)(W + (size_t)(v0 + r + k) * VV + c0 + q * 4);
            tile[r + k][q * 4 + 0] = x.x;
            tile[r + k][q * 4 + 1] = x.y;
            tile[r + k][q * 4 + 2] = x.z;
            tile[r + k][q * 4 + 3] = x.w;
        }
    }
    // Stage the 4 per-batch additive slices for this v-range.
    for (int i = tid; i < BB * VT; i += 256) {
        addl[i / VT][i % VT] = add[(size_t)(i / VT) * VV + v0 + (i % VT)];
    }
    __syncthreads();

    const int start = offsets[cb];
    const int end = offsets[cb + 1];
    const int v = tid & (VT - 1);        // 0..127
    const int which = tid >> 7;          // 2 tokens in flight
    for (int i = start + which; i < end; i += 2) {
        const int pk = sorted[i];
        const int n = pk >> 13;
        const int cl = (pk & (VV - 1)) - c0;
        const int b = n >> 12;           // n / LL
        out[(size_t)n * VV + v0 + v] = tile[v][cl] + addl[b][v];
    }
}

// ---------------------------------------------------------------------------
// Fallback (workspace too small): direct strided column gather.
__global__ void gather_direct_kernel(const int* __restrict__ idx,
                                     const float* __restrict__ W,
                                     const float* __restrict__ add,
                                     float* __restrict__ out) {
    const int n = blockIdx.x;
    const int b = n >> 12;
    int c = idx[n];
    c = min(max(c, 0), VV - 1);
    const int v0 = blockIdx.y * (VV / 4);
    for (int v = v0 + threadIdx.x; v < v0 + VV / 4; v += 256) {
        out[(size_t)n * VV + v] = W[(size_t)v * VV + c] + add[b * VV + v];
    }
}

extern "C" void kernel_launch(void* const* d_in, const int* in_sizes, int n_in,
                              void* d_out, int out_size, void* d_ws,
                              size_t ws_size, hipStream_t stream) {
    const int* indices = (const int*)d_in[0];   // [B, L] int32
    const float* sigma = (const float*)d_in[1]; // [B]
    const float* W = (const float*)d_in[2];     // [V, V]
    const float* bias = (const float*)d_in[3];  // [V]
    float* out = (float*)d_out;                 // [B, L, V]

    float* add = (float*)d_ws;                          // B*V floats = 128 KB
    const size_t add_bytes = (size_t)BB * VV * sizeof(float);
    int* sorted = (int*)((char*)d_ws + add_bytes);      // NN ints = 64 KB
    const size_t sorted_bytes = (size_t)NN * sizeof(int);
    int* offsets = (int*)((char*)d_ws + add_bytes + sorted_bytes); // NB+1 ints
    const size_t off_bytes = (size_t)(NB + 1) * sizeof(int);

    rowsum_kernel<<<VV, 256, 0, stream>>>(W, sigma, bias, add);

    if (ws_size >= add_bytes + sorted_bytes + off_bytes) {
        bucket_kernel<<<1, 256, 0, stream>>>(indices, sorted, offsets);
        gather_fused_kernel<<<dim3(NB, VV / VT), 256, 0, stream>>>(
            sorted, offsets, W, add, out);
    } else {
        gather_direct_kernel<<<dim3(NN, 4), 256, 0, stream>>>(indices, W, add, out);
    }
}

// Round 3
// 771.043 us; speedup vs baseline: 1.0542x; 1.0542x over previous
//
#include <hip/hip_runtime.h>

// Problem constants (from reference): B=4, L=4096, V=8192.
#define BB 4
#define LL 4096
#define VV 8192
#define NN (BB * LL)          // 16384 tokens
#define SIGMA_SCALE 0.01f

// Bucketing: tokens grouped by idx >> 6 (64-wide column buckets).
#define CW 64                 // columns per bucket / tile width
#define NB (VV / CW)          // 128 buckets
#define VT 128                // v-rows per tile
#define VT4 (VT / 4)          // 32 float4 per token segment
#define VTP (VT4 + 1)         // padded row stride in float4 (33)

typedef float f4 __attribute__((ext_vector_type(4)));  // native vec for nt-store

// out[b,l,v] = W[v, idx[b,l]] + 0.01*sigma[b]*rowsum(W)[v] + bias[v]

// ---------------------------------------------------------------------------
// Kernel 1: per-row sum of W, fused into per-(b,v) additive table:
//   add[b*V + v] = SIGMA_SCALE * sigma[b] * sum_j W[v,j] + bias[v]
// Side effect we rely on: streams all of W through L2/L3 right before the
// gather kernel re-reads it (L3 = 256 MiB = sizeof(W)).
__global__ void rowsum_kernel(const float* __restrict__ W,
                              const float* __restrict__ sigma,
                              const float* __restrict__ bias,
                              float* __restrict__ add) {
    __shared__ float red[256];
    const int v = blockIdx.x;
    const float4* row4 = (const float4*)(W + (size_t)v * VV);
    float s = 0.f;
#pragma unroll
    for (int j = threadIdx.x; j < VV / 4; j += 256) {
        float4 x = row4[j];
        s += x.x + x.y + x.z + x.w;
    }
    red[threadIdx.x] = s;
    __syncthreads();
    for (int off = 128; off > 0; off >>= 1) {
        if (threadIdx.x < off) red[threadIdx.x] += red[threadIdx.x + off];
        __syncthreads();
    }
    if (threadIdx.x < BB) {
        add[threadIdx.x * VV + v] =
            SIGMA_SCALE * sigma[threadIdx.x] * red[0] + bias[v];
    }
}

// ---------------------------------------------------------------------------
// Kernel 2: bucket the 16384 tokens by column-tile (idx >> 6).
// Single block, 256 threads. Output: sorted[] packed as (n<<13)|c,
// offsets[NB+1] bucket boundaries.
__global__ void bucket_kernel(const int* __restrict__ idx,
                              int* __restrict__ sorted,
                              int* __restrict__ offsets) {
    __shared__ int hist[NB];
    __shared__ int base[NB + 1];
    __shared__ int cursor[NB];
    const int tid = threadIdx.x;
    for (int i = tid; i < NB; i += 256) hist[i] = 0;
    __syncthreads();
    for (int n = tid; n < NN; n += 256) {
        int c = idx[n];
        c = min(max(c, 0), VV - 1);
        atomicAdd(&hist[c >> 6], 1);
    }
    __syncthreads();
    if (tid == 0) {
        int s = 0;
        for (int i = 0; i < NB; ++i) { base[i] = s; s += hist[i]; }
        base[NB] = s;
    }
    __syncthreads();
    for (int i = tid; i <= NB; i += 256) offsets[i] = base[i];
    for (int i = tid; i < NB; i += 256) cursor[i] = 0;
    __syncthreads();
    for (int n = tid; n < NN; n += 256) {
        int c = idx[n];
        c = min(max(c, 0), VV - 1);
        const int bkt = c >> 6;
        const int pos = base[bkt] + atomicAdd(&cursor[bkt], 1);
        sorted[pos] = (n << 13) | c;
    }
}

// ---------------------------------------------------------------------------
// Kernel 3: fused transpose-gather. Block (cb, vb) loads W[vb*VT .. +VT,
// cb*64 .. +64] into LDS TRANSPOSED (tileT[c_local][v_local]); then for each
// token in bucket cb, a 32-lane group streams one contiguous 512 B LDS row
// (ds_read_b128, conflict-free) and nontemporal-float4-stores
// out[n, vb*VT .. +VT] = tileT[cl][:] + add[b, vb*VT .. +VT].
// W is read from HBM exactly once across the whole grid; out writes are
// no-allocate so L2/L3 keep serving W.
__global__ __launch_bounds__(256) void gather_fused_kernel(
    const int* __restrict__ sorted, const int* __restrict__ offsets,
    const float* __restrict__ W, const float* __restrict__ add,
    float* __restrict__ out) {
    __shared__ f4 tileT4[CW][VTP];       // [64][33] f4; row = one token segment
    __shared__ f4 addl4[BB][VT4];
    float* tileT = (float*)tileT4;       // row stride 4*VTP = 132 floats
    const int cb = blockIdx.x;           // 0..NB-1
    const int vb = blockIdx.y;           // 0..VV/VT-1
    const int c0 = cb * CW;
    const int v0 = vb * VT;
    const int tid = threadIdx.x;         // 0..255

    // Stage W tile transposed. Global read: 16 lanes x float4 = 256 B per row
    // segment, fully coalesced. LDS write: 4 scalar stores (8-way conflict,
    // ~550 cyc/wave — hidden under the 32 KiB HBM fetch).
    {
        const int r = tid >> 4;          // 0..15 (v-row within pass)
        const int q = tid & 15;          // float4 slot within row (c-chunk)
#pragma unroll
        for (int k = 0; k < VT; k += 16) {
            const int row = r + k;       // v_local
            float4 x = *(const float4*)(W + (size_t)(v0 + row) * VV + c0 + q * 4);
            tileT[(4 * q + 0) * (4 * VTP) + row] = x.x;
            tileT[(4 * q + 1) * (4 * VTP) + row] = x.y;
            tileT[(4 * q + 2) * (4 * VTP) + row] = x.z;
            tileT[(4 * q + 3) * (4 * VTP) + row] = x.w;
        }
    }
    // Stage the 4 per-batch additive slices for this v-range (as float4).
    if (tid < BB * VT4) {
        const int b = tid >> 5;          // 0..3
        const int j = tid & 31;          // 0..31
        addl4[b][j] = *(const f4*)(add + (size_t)b * VV + v0 + 4 * j);
    }
    __syncthreads();

    const int start = offsets[cb];
    const int end = offsets[cb + 1];
    const int slot = tid >> 5;           // 8 tokens in flight per block
    const int j = tid & 31;              // float4 lane within token segment
    for (int i = start + slot; i < end; i += 8) {
        const int pk = sorted[i];
        const int n = pk >> 13;
        const int cl = (pk & (VV - 1)) - c0;
        const int b = n >> 12;           // n / LL
        f4 t = tileT4[cl][j];            // contiguous 512 B per token group
        f4 a = addl4[b][j];
        f4 o = t + a;
        f4* dst = (f4*)(out + (size_t)n * VV + v0) + j;
        __builtin_nontemporal_store(o, dst);
    }
}

// ---------------------------------------------------------------------------
// Fallback (workspace too small): direct strided column gather.
__global__ void gather_direct_kernel(const int* __restrict__ idx,
                                     const float* __restrict__ W,
                                     const float* __restrict__ add,
                                     float* __restrict__ out) {
    const int n = blockIdx.x;
    const int b = n >> 12;
    int c = idx[n];
    c = min(max(c, 0), VV - 1);
    const int v0 = blockIdx.y * (VV / 4);
    for (int v = v0 + threadIdx.x; v < v0 + VV / 4; v += 256) {
        out[(size_t)n * VV + v] = W[(size_t)v * VV + c] + add[b * VV + v];
    }
}

extern "C" void kernel_launch(void* const* d_in, const int* in_sizes, int n_in,
                              void* d_out, int out_size, void* d_ws,
                              size_t ws_size, hipStream_t stream) {
    const int* indices = (const int*)d_in[0];   // [B, L] int32
    const float* sigma = (const float*)d_in[1]; // [B]
    const float* W = (const float*)d_in[2];     // [V, V]
    const float* bias = (const float*)d_in[3];  // [V]
    float* out = (float*)d_out;                 // [B, L, V]

    float* add = (float*)d_ws;                          // B*V floats = 128 KB
    const size_t add_bytes = (size_t)BB * VV * sizeof(float);
    int* sorted = (int*)((char*)d_ws + add_bytes);      // NN ints = 64 KB
    const size_t sorted_bytes = (size_t)NN * sizeof(int);
    int* offsets = (int*)((char*)d_ws + add_bytes + sorted_bytes); // NB+1 ints
    const size_t off_bytes = (size_t)(NB + 1) * sizeof(int);

    rowsum_kernel<<<VV, 256, 0, stream>>>(W, sigma, bias, add);

    if (ws_size >= add_bytes + sorted_bytes + off_bytes) {
        bucket_kernel<<<1, 256, 0, stream>>>(indices, sorted, offsets);
        gather_fused_kernel<<<dim3(NB, VV / VT), 256, 0, stream>>>(
            sorted, offsets, W, add, out);
    } else {
        gather_direct_kernel<<<dim3(NN, 4), 256, 0, stream>>>(indices, W, add, out);
    }
}